// Round 7
// baseline (679.308 us; speedup 1.0000x reference)
//
#include <hip/hip_runtime.h>
#include <hip/hip_bf16.h>

typedef __bf16 bf16x8 __attribute__((ext_vector_type(8)));
typedef __bf16 bf16x4 __attribute__((ext_vector_type(4)));
typedef float floatx4 __attribute__((ext_vector_type(4)));
using bf16 = __hip_bfloat16;

#define S_    2048
#define NHEAD 16
#define LOG2E 1.4426950408889634f

// Async global->LDS DMA, 16 B per lane (lane i -> lds + i*16).
__device__ __forceinline__ void load_lds16(const bf16* g, void* lds) {
  __builtin_amdgcn_global_load_lds((const __attribute__((address_space(1))) void*)g,
                                   (__attribute__((address_space(3))) void*)lds, 16, 0, 0);
}

// ---------------------------------------------------------------------------
// Cast fp32 -> bf16, 4 elems/thread.
// ---------------------------------------------------------------------------
__global__ void cast_f32_bf16_kernel(const float* __restrict__ src, bf16* __restrict__ dst) {
  int i = (blockIdx.x * 256 + threadIdx.x) * 4;
  float4 v = *(const float4*)(src + i);
  bf16 o[4] = {__float2bfloat16(v.x), __float2bfloat16(v.y),
               __float2bfloat16(v.z), __float2bfloat16(v.w)};
  *(uint2*)(dst + i) = *(const uint2*)o;
}

// ---------------------------------------------------------------------------
// Transpose+cast weights: src fp32 [K=1024][N=1024] -> dst bf16 [N][K].
// ---------------------------------------------------------------------------
__global__ void transpose_w_kernel(const float* __restrict__ wq, const float* __restrict__ wk,
                                   const float* __restrict__ wv, const float* __restrict__ wo,
                                   bf16* __restrict__ wt_qkv, bf16* __restrict__ wt_o) {
  __shared__ bf16 tile[32][33];
  int mat = blockIdx.z;
  const float* src = (mat == 0) ? wq : (mat == 1) ? wk : (mat == 2) ? wv : wo;
  bf16* dst = (mat == 3) ? wt_o : wt_qkv + mat * 1024 * 1024;
  int tx = threadIdx.x, ty = threadIdx.y;
  int n0 = blockIdx.x * 32, k0 = blockIdx.y * 32;
#pragma unroll
  for (int j = 0; j < 32; j += 8)
    tile[ty + j][tx] = __float2bfloat16(src[(k0 + ty + j) * 1024 + n0 + tx]);
  __syncthreads();
#pragma unroll
  for (int j = 0; j < 32; j += 8)
    dst[(n0 + ty + j) * 1024 + k0 + tx] = tile[tx][ty + j];
}

// ---------------------------------------------------------------------------
// T5 bias LUT, PRE-SCALED by log2(e): tab[h*4096 + (delta+2048)].
// ---------------------------------------------------------------------------
__global__ void bias_table_kernel(const float* __restrict__ rel_bias, float* __restrict__ tab) {
  int idx = blockIdx.x * 256 + threadIdx.x;   // 16*4096 = 65536
  int h = idx >> 12, j = idx & 4095;
  int delta = j - 2048;                        // k - q
  int rb = (delta > 0) ? 16 : 0;
  int rpa = delta < 0 ? -delta : delta;
  int bsmall;
  if (rpa < 8) {
    bsmall = rpa;
  } else {
    int lg = 25 - __clz(rpa * rpa);
    bsmall = 8 + lg;
    if (bsmall > 15) bsmall = 15;
  }
  tab[idx] = rel_bias[(rb + bsmall) * 16 + h] * LOG2E;
}

// ---------------------------------------------------------------------------
// QKV GEMM: head-major epilogue (qh/kh/vh[bh][s][64]); m97-style staging.
// ---------------------------------------------------------------------------
__global__ __launch_bounds__(256) void gemm_qkv_kernel(const bf16* __restrict__ A,
                                                       const bf16* __restrict__ Bt,
                                                       bf16* __restrict__ qh,
                                                       bf16* __restrict__ kh,
                                                       bf16* __restrict__ vh) {
  const int K = 1024;
  __shared__ bf16 As[128 * 32];
  __shared__ bf16 Bs[128 * 32];
  int t = threadIdx.x;
  int m0 = blockIdx.y * 128, n0 = blockIdx.x * 128;
  int w = t >> 6, lane = t & 63, ln = lane & 15, quad = lane >> 4;
  int wr = w >> 1, wc = w & 1;
  floatx4 acc[4][4];
  floatx4 zero = {0.f, 0.f, 0.f, 0.f};
#pragma unroll
  for (int i = 0; i < 4; i++)
#pragma unroll
    for (int j = 0; j < 4; j++) acc[i][j] = zero;

  int r = t >> 2, c = (t & 3) * 8;
  const bf16* Ag = A + (long)(m0 + r) * K + c;
  const bf16* Bg = Bt + (long)(n0 + r) * K + c;
  char* ldsA0 = (char*)As + w * 1024;
  char* ldsA1 = ldsA0 + 4096;
  char* ldsB0 = (char*)Bs + w * 1024;
  char* ldsB1 = ldsB0 + 4096;

  for (int k0 = 0; k0 < K; k0 += 32) {
    load_lds16(Ag + k0, ldsA0);
    load_lds16(Ag + (long)64 * K + k0, ldsA1);
    load_lds16(Bg + k0, ldsB0);
    load_lds16(Bg + (long)64 * K + k0, ldsB1);
    __syncthreads();
    bf16x8 af[4], bfv[4];
#pragma unroll
    for (int i = 0; i < 4; i++)
      af[i] = *(const bf16x8*)&As[(wr * 64 + i * 16 + ln) * 32 + quad * 8];
#pragma unroll
    for (int j = 0; j < 4; j++)
      bfv[j] = *(const bf16x8*)&Bs[(wc * 64 + j * 16 + ln) * 32 + quad * 8];
#pragma unroll
    for (int i = 0; i < 4; i++)
#pragma unroll
      for (int j = 0; j < 4; j++)
        acc[i][j] = __builtin_amdgcn_mfma_f32_16x16x32_bf16(af[i], bfv[j], acc[i][j], 0, 0, 0);
    __syncthreads();
  }

  int nb = n0 + wc * 64;
  int type = nb >> 10, h = (nb >> 6) & 15;
  bf16* dst = (type == 0) ? qh : (type == 1) ? kh : vh;
#pragma unroll
  for (int i = 0; i < 4; i++)
#pragma unroll
    for (int j = 0; j < 4; j++) {
      int d = j * 16 + ln;
#pragma unroll
      for (int rr = 0; rr < 4; rr++) {
        int sg = m0 + wr * 64 + i * 16 + quad * 4 + rr;
        int b = sg >> 11, s = sg & 2047;
        dst[((long)((b * 16 + h) * 2048 + s)) * 64 + d] = __float2bfloat16(acc[i][j][rr]);
      }
    }
}

// ---------------------------------------------------------------------------
// Repack K and V into MFMA-fragment-major layouts (1KB coalesced fragments).
// ---------------------------------------------------------------------------
__global__ void repack_kv_kernel(const bf16* __restrict__ kh, const bf16* __restrict__ vh,
                                 bf16* __restrict__ kf, bf16* __restrict__ vf) {
  __shared__ __bf16 vl[64 * 72];
  int bh = blockIdx.y, k0 = blockIdx.x * 64, t = threadIdx.x;
  long base = ((long)bh * 2048 + k0) * 64;

#pragma unroll
  for (int p = 0; p < 2; p++) {
    int c = t + p * 256;
    int blk16 = c >> 7, rem = c & 127;
    int f = rem >> 6, quad = (rem >> 4) & 3, ln = rem & 15;
    bf16x8 v = *(const bf16x8*)(kh + base + (blk16 * 16 + ln) * 64 + f * 32 + quad * 8);
    *(bf16x8*)(kf + base + blk16 * 1024 + f * 512 + quad * 128 + ln * 8) = v;
  }

#pragma unroll
  for (int p = 0; p < 2; p++) {
    int cc = t + p * 256;
    int row = cc >> 3, colc = cc & 7;
    *(bf16x8*)&vl[row * 72 + colc * 8] = *(const bf16x8*)(vh + base + row * 64 + colc * 8);
  }
  __syncthreads();
#pragma unroll
  for (int p = 0; p < 2; p++) {
    int c = t + p * 256;
    int blk32 = c >> 8, rem = c & 255;
    int dt = rem >> 6, quad = (rem >> 4) & 3, ln = rem & 15;
    int d = dt * 16 + ln;
    bf16x8 pk;
#pragma unroll
    for (int j = 0; j < 8; j++) pk[j] = vl[(blk32 * 32 + quad * 8 + j) * 72 + d];
    *(bf16x8*)(vf + base + blk32 * 2048 + dt * 512 + quad * 128 + ln * 8) = pk;
  }
}

// ---------------------------------------------------------------------------
// Flash attention, barrier-free, occupancy-optimized. Grid (32 bh, 32 qblk)
// = 1024 blocks = 4 blocks/CU; 4 waves x 16 q rows. K/V fragments register-
// prefetched one 64-k tile ahead (coalesced 1KB frag-major segments; the 4
// waves of a block hit identical lines -> L1 broadcast). LDS = per-wave 2KB
// P buffer only. __launch_bounds__(256,4) caps VGPR at 128 for 16 waves/CU.
// ---------------------------------------------------------------------------
__global__ __launch_bounds__(256, 4) void attn_kernel(const bf16* __restrict__ qh,
                                                      const bf16* __restrict__ kf,
                                                      const bf16* __restrict__ vf,
                                                      const float* __restrict__ btab,
                                                      bf16* __restrict__ ctx) {
  __shared__ char PsRaw[4 * 2048];             // per-wave 2KB P buffer
  int t = threadIdx.x, w = t >> 6, lane = t & 63, ln = lane & 15, quad = lane >> 4;
  int bh = blockIdx.x, b = bh >> 4, h = bh & 15;
  int qw = blockIdx.y * 64 + w * 16;           // this wave's first q row

  const bf16* qbase = qh + (long)bh * S_ * 64;
  const bf16* kfb = kf + (long)bh * S_ * 64;
  const bf16* vfb = vf + (long)bh * S_ * 64;
  const float* bt = btab + h * 4096;
  char* myPs = PsRaw + w * 2048;
  int foff = quad * 128 + ln * 8;              // lane elem offset inside 1KB frag

  // Q as B-operand: lane holds q = qw+ln, d = f*32+quad*8+j
  bf16x8 Qf0, Qf1;
  {
    const bf16* qr = qbase + (long)(qw + ln) * 64;
    Qf0 = *(const bf16x8*)(qr + quad * 8);
    Qf1 = *(const bf16x8*)(qr + 32 + quad * 8);
  }

  float cneg = bt[0], cpos = bt[4095];
  float l_acc = 0.f;
  floatx4 o[4];
  floatx4 zero = {0.f, 0.f, 0.f, 0.f};
#pragma unroll
  for (int dt = 0; dt < 4; dt++) o[dt] = zero;

  // preload K,V for k0 = 0 (all loads single coalesced 1KB segments)
  bf16x8 Kc[4][2], Vc[4][2];
#pragma unroll
  for (int tile = 0; tile < 4; tile++) {
    Kc[tile][0] = *(const bf16x8*)(kfb + tile * 1024 + foff);
    Kc[tile][1] = *(const bf16x8*)(kfb + tile * 1024 + 512 + foff);
  }
#pragma unroll
  for (int f = 0; f < 2; f++)
#pragma unroll
    for (int dt = 0; dt < 4; dt++)
      Vc[dt][f] = *(const bf16x8*)(vfb + f * 2048 + dt * 512 + foff);

  for (int k0 = 0; k0 < S_; k0 += 64) {
    int kn = k0 + 64;
    bf16x8 Kn[4][2], Vn[4][2];
    if (kn < S_) {
      const bf16* kp = kfb + (long)kn * 64;
      const bf16* vp = vfb + (long)kn * 64;
#pragma unroll
      for (int tile = 0; tile < 4; tile++) {
        Kn[tile][0] = *(const bf16x8*)(kp + tile * 1024 + foff);
        Kn[tile][1] = *(const bf16x8*)(kp + tile * 1024 + 512 + foff);
      }
#pragma unroll
      for (int f = 0; f < 2; f++)
#pragma unroll
        for (int dt = 0; dt < 4; dt++)
          Vn[dt][f] = *(const bf16x8*)(vp + f * 2048 + dt * 512 + foff);
    }

    // S^T tiles: A = K, B = Q -> col = q = ln, row = k = quad*4+rr
    floatx4 st[4];
#pragma unroll
    for (int tile = 0; tile < 4; tile++) {
      st[tile] = __builtin_amdgcn_mfma_f32_16x16x32_bf16(Kc[tile][0], Qf0, zero, 0, 0, 0);
      st[tile] = __builtin_amdgcn_mfma_f32_16x16x32_bf16(Kc[tile][1], Qf1, st[tile], 0, 0, 0);
    }

    bool near = (k0 > qw - 192) && (k0 < qw + 144);
    if (near) {
#pragma unroll
      for (int tile = 0; tile < 4; tile++) {
        int bidx = k0 + tile * 16 + quad * 4 - (qw + ln) + 2048;
        float p0 = __builtin_amdgcn_exp2f(fmaf(st[tile][0], LOG2E, bt[bidx + 0]));
        float p1 = __builtin_amdgcn_exp2f(fmaf(st[tile][1], LOG2E, bt[bidx + 1]));
        float p2 = __builtin_amdgcn_exp2f(fmaf(st[tile][2], LOG2E, bt[bidx + 2]));
        float p3 = __builtin_amdgcn_exp2f(fmaf(st[tile][3], LOG2E, bt[bidx + 3]));
        l_acc += (p0 + p1) + (p2 + p3);
        bf16x4 pk = {(__bf16)p0, (__bf16)p1, (__bf16)p2, (__bf16)p3};
        int chunk = tile * 2 + (quad >> 1);
        *(bf16x4*)(myPs + (ln * 8 + (chunk ^ (ln & 7))) * 16 + (quad & 1) * 8) = pk;
      }
    } else {
      float cb = (k0 > qw) ? cpos : cneg;
#pragma unroll
      for (int tile = 0; tile < 4; tile++) {
        float p0 = __builtin_amdgcn_exp2f(fmaf(st[tile][0], LOG2E, cb));
        float p1 = __builtin_amdgcn_exp2f(fmaf(st[tile][1], LOG2E, cb));
        float p2 = __builtin_amdgcn_exp2f(fmaf(st[tile][2], LOG2E, cb));
        float p3 = __builtin_amdgcn_exp2f(fmaf(st[tile][3], LOG2E, cb));
        l_acc += (p0 + p1) + (p2 + p3);
        bf16x4 pk = {(__bf16)p0, (__bf16)p1, (__bf16)p2, (__bf16)p3};
        int chunk = tile * 2 + (quad >> 1);
        *(bf16x4*)(myPs + (ln * 8 + (chunk ^ (ln & 7))) * 16 + (quad & 1) * 8) = pk;
      }
    }

    // PV: A = P from per-wave LDS, B = V (prefetched registers)
    bf16x8 Pf0 = *(const bf16x8*)(myPs + (ln * 8 + (quad ^ (ln & 7))) * 16);
    bf16x8 Pf1 = *(const bf16x8*)(myPs + (ln * 8 + ((4 + quad) ^ (ln & 7))) * 16);
#pragma unroll
    for (int dt = 0; dt < 4; dt++) {
      o[dt] = __builtin_amdgcn_mfma_f32_16x16x32_bf16(Pf0, Vc[dt][0], o[dt], 0, 0, 0);
      o[dt] = __builtin_amdgcn_mfma_f32_16x16x32_bf16(Pf1, Vc[dt][1], o[dt], 0, 0, 0);
    }

    if (kn < S_) {
#pragma unroll
      for (int tile = 0; tile < 4; tile++) {
        Kc[tile][0] = Kn[tile][0]; Kc[tile][1] = Kn[tile][1];
        Vc[tile][0] = Vn[tile][0]; Vc[tile][1] = Vn[tile][1];
      }
    }
  }

  // final l reduction across quads, then scale+store
  l_acc += __shfl_xor(l_acc, 16);
  l_acc += __shfl_xor(l_acc, 32);
#pragma unroll
  for (int rr = 0; rr < 4; rr++) {
    float linv = 1.0f / __shfl(l_acc, quad * 4 + rr);
    int q = qw + quad * 4 + rr;
#pragma unroll
    for (int dt = 0; dt < 4; dt++)
      ctx[(long)(b * S_ + q) * 1024 + h * 64 + dt * 16 + ln] =
          __float2bfloat16(o[dt][rr] * linv);
  }
}

// ---------------------------------------------------------------------------
// Out-proj GEMM: C[M][N] = A[M][K] * Bt[N][K]^T (fp32 out), m97-style staging.
// ---------------------------------------------------------------------------
__global__ __launch_bounds__(256) void gemm_bt_kernel(const bf16* __restrict__ A,
                                                      const bf16* __restrict__ Bt,
                                                      float* __restrict__ C,
                                                      int M, int N, int K) {
  __shared__ bf16 As[128 * 32];
  __shared__ bf16 Bs[128 * 32];
  int t = threadIdx.x;
  int m0 = blockIdx.y * 128, n0 = blockIdx.x * 128;
  int w = t >> 6, lane = t & 63, ln = lane & 15, quad = lane >> 4;
  int wr = w >> 1, wc = w & 1;
  floatx4 acc[4][4];
  floatx4 zero = {0.f, 0.f, 0.f, 0.f};
#pragma unroll
  for (int i = 0; i < 4; i++)
#pragma unroll
    for (int j = 0; j < 4; j++) acc[i][j] = zero;

  int r = t >> 2, c = (t & 3) * 8;
  const bf16* Ag = A + (long)(m0 + r) * K + c;
  const bf16* Bg = Bt + (long)(n0 + r) * K + c;
  char* ldsA0 = (char*)As + w * 1024;
  char* ldsA1 = ldsA0 + 4096;
  char* ldsB0 = (char*)Bs + w * 1024;
  char* ldsB1 = ldsB0 + 4096;

  for (int k0 = 0; k0 < K; k0 += 32) {
    load_lds16(Ag + k0, ldsA0);
    load_lds16(Ag + (long)64 * K + k0, ldsA1);
    load_lds16(Bg + k0, ldsB0);
    load_lds16(Bg + (long)64 * K + k0, ldsB1);
    __syncthreads();
    bf16x8 af[4], bfv[4];
#pragma unroll
    for (int i = 0; i < 4; i++)
      af[i] = *(const bf16x8*)&As[(wr * 64 + i * 16 + ln) * 32 + quad * 8];
#pragma unroll
    for (int j = 0; j < 4; j++)
      bfv[j] = *(const bf16x8*)&Bs[(wc * 64 + j * 16 + ln) * 32 + quad * 8];
#pragma unroll
    for (int i = 0; i < 4; i++)
#pragma unroll
      for (int j = 0; j < 4; j++)
        acc[i][j] = __builtin_amdgcn_mfma_f32_16x16x32_bf16(af[i], bfv[j], acc[i][j], 0, 0, 0);
    __syncthreads();
  }

#pragma unroll
  for (int i = 0; i < 4; i++)
#pragma unroll
    for (int j = 0; j < 4; j++)
#pragma unroll
      for (int rr = 0; rr < 4; rr++)
        C[(long)(m0 + wr * 64 + i * 16 + quad * 4 + rr) * N + n0 + wc * 64 + j * 16 + ln] =
            acc[i][j][rr];
}

// ---------------------------------------------------------------------------
extern "C" void kernel_launch(void* const* d_in, const int* in_sizes, int n_in,
                              void* d_out, int out_size, void* d_ws, size_t ws_size,
                              hipStream_t stream) {
  (void)in_sizes; (void)n_in; (void)out_size; (void)ws_size;
  const float* hidden   = (const float*)d_in[0];
  const float* Wq       = (const float*)d_in[1];
  const float* Wk       = (const float*)d_in[2];
  const float* Wv       = (const float*)d_in[3];
  const float* Wo       = (const float*)d_in[4];
  const float* rel_bias = (const float*)d_in[5];

  char* ws = (char*)d_ws;
  bf16*  hbf    = (bf16*)(ws + 0);                 //  8 MB [4096][1024]
  bf16*  wt_qkv = (bf16*)(ws + 8388608);           //  6 MB
  bf16*  wt_o   = (bf16*)(ws + 14680064);          //  2 MB
  float* btab   = (float*)(ws + 16777216);         // 256 KB
  bf16*  qh     = (bf16*)(ws + 17039360);          //  8 MB [32][2048][64]
  bf16*  kh     = (bf16*)(ws + 25427968);          //  8 MB
  bf16*  vh     = (bf16*)(ws + 33816576);          //  8 MB
  bf16*  kf     = (bf16*)(ws + 42205184);          //  8 MB frag-major K
  bf16*  vf     = (bf16*)(ws + 50593792);          //  8 MB frag-major V
  bf16*  ctx    = (bf16*)(ws + 58982400);          //  8 MB

  cast_f32_bf16_kernel<<<dim3(4096), dim3(256), 0, stream>>>(hidden, hbf);
  transpose_w_kernel<<<dim3(32, 32, 4), dim3(32, 8), 0, stream>>>(Wq, Wk, Wv, Wo, wt_qkv, wt_o);
  bias_table_kernel<<<dim3(256), dim3(256), 0, stream>>>(rel_bias, btab);
  gemm_qkv_kernel<<<dim3(24, 32), dim3(256), 0, stream>>>(hbf, wt_qkv, qh, kh, vh);
  repack_kv_kernel<<<dim3(32, 32), dim3(256), 0, stream>>>(kh, vh, kf, vf);
  attn_kernel<<<dim3(32, 32), dim3(256), 0, stream>>>(qh, kf, vf, btab, ctx);
  gemm_bt_kernel<<<dim3(8, 32), dim3(256), 0, stream>>>(ctx, wt_o, (float*)d_out, 4096, 1024, 1024);
}

// Round 8
// 201.573 us; speedup vs baseline: 3.3700x; 3.3700x over previous
//
#include <hip/hip_runtime.h>
#include <hip/hip_bf16.h>

typedef __bf16 bf16x8 __attribute__((ext_vector_type(8)));
typedef __bf16 bf16x4 __attribute__((ext_vector_type(4)));
typedef float floatx4 __attribute__((ext_vector_type(4)));
using bf16 = __hip_bfloat16;

#define S_    2048
#define NHEAD 16
#define LOG2E 1.4426950408889634f

// Async global->LDS DMA, 16 B per lane (lane i -> lds + i*16).
__device__ __forceinline__ void load_lds16(const bf16* g, void* lds) {
  __builtin_amdgcn_global_load_lds((const __attribute__((address_space(1))) void*)g,
                                   (__attribute__((address_space(3))) void*)lds, 16, 0, 0);
}

// ---------------------------------------------------------------------------
// Cast fp32 -> bf16, 4 elems/thread.
// ---------------------------------------------------------------------------
__global__ void cast_f32_bf16_kernel(const float* __restrict__ src, bf16* __restrict__ dst) {
  int i = (blockIdx.x * 256 + threadIdx.x) * 4;
  float4 v = *(const float4*)(src + i);
  bf16 o[4] = {__float2bfloat16(v.x), __float2bfloat16(v.y),
               __float2bfloat16(v.z), __float2bfloat16(v.w)};
  *(uint2*)(dst + i) = *(const uint2*)o;
}

// ---------------------------------------------------------------------------
// Transpose+cast weights: src fp32 [K=1024][N=1024] -> dst bf16 [N][K].
// ---------------------------------------------------------------------------
__global__ void transpose_w_kernel(const float* __restrict__ wq, const float* __restrict__ wk,
                                   const float* __restrict__ wv, const float* __restrict__ wo,
                                   bf16* __restrict__ wt_qkv, bf16* __restrict__ wt_o) {
  __shared__ bf16 tile[32][33];
  int mat = blockIdx.z;
  const float* src = (mat == 0) ? wq : (mat == 1) ? wk : (mat == 2) ? wv : wo;
  bf16* dst = (mat == 3) ? wt_o : wt_qkv + mat * 1024 * 1024;
  int tx = threadIdx.x, ty = threadIdx.y;
  int n0 = blockIdx.x * 32, k0 = blockIdx.y * 32;
#pragma unroll
  for (int j = 0; j < 32; j += 8)
    tile[ty + j][tx] = __float2bfloat16(src[(k0 + ty + j) * 1024 + n0 + tx]);
  __syncthreads();
#pragma unroll
  for (int j = 0; j < 32; j += 8)
    dst[(n0 + ty + j) * 1024 + k0 + tx] = tile[tx][ty + j];
}

// ---------------------------------------------------------------------------
// T5 bias LUT, PRE-SCALED by log2(e): tab[h*4096 + (delta+2048)].
// ---------------------------------------------------------------------------
__global__ void bias_table_kernel(const float* __restrict__ rel_bias, float* __restrict__ tab) {
  int idx = blockIdx.x * 256 + threadIdx.x;   // 16*4096 = 65536
  int h = idx >> 12, j = idx & 4095;
  int delta = j - 2048;                        // k - q
  int rb = (delta > 0) ? 16 : 0;
  int rpa = delta < 0 ? -delta : delta;
  int bsmall;
  if (rpa < 8) {
    bsmall = rpa;
  } else {
    int lg = 25 - __clz(rpa * rpa);
    bsmall = 8 + lg;
    if (bsmall > 15) bsmall = 15;
  }
  tab[idx] = rel_bias[(rb + bsmall) * 16 + h] * LOG2E;
}

// ---------------------------------------------------------------------------
// QKV GEMM, m97-style staging. Epilogue writes q head-major (qh[bh][s][64])
// and K/V directly in MFMA-fragment-major layouts (kf/vf) so the old
// repack_kv kernel is deleted.
//  kf(k,d) = bh*131072 + (k&~15)*64 + (d>>5)*512 + ((d>>3)&3)*128 + (k&15)*8 + (d&7)
//  vf(k,d) = bh*131072 + (k&~31)*64 + (d>>4)*512 + ((k>>3)&3)*128 + (d&15)*8 + (k&7)
// ---------------------------------------------------------------------------
__global__ __launch_bounds__(256) void gemm_qkv_kernel(const bf16* __restrict__ A,
                                                       const bf16* __restrict__ Bt,
                                                       bf16* __restrict__ qh,
                                                       bf16* __restrict__ kf,
                                                       bf16* __restrict__ vf) {
  const int K = 1024;
  __shared__ bf16 As[128 * 32];
  __shared__ bf16 Bs[128 * 32];
  int t = threadIdx.x;
  int m0 = blockIdx.y * 128, n0 = blockIdx.x * 128;
  int w = t >> 6, lane = t & 63, ln = lane & 15, quad = lane >> 4;
  int wr = w >> 1, wc = w & 1;
  floatx4 acc[4][4];
  floatx4 zero = {0.f, 0.f, 0.f, 0.f};
#pragma unroll
  for (int i = 0; i < 4; i++)
#pragma unroll
    for (int j = 0; j < 4; j++) acc[i][j] = zero;

  int r = t >> 2, c = (t & 3) * 8;
  const bf16* Ag = A + (long)(m0 + r) * K + c;
  const bf16* Bg = Bt + (long)(n0 + r) * K + c;
  char* ldsA0 = (char*)As + w * 1024;
  char* ldsA1 = ldsA0 + 4096;
  char* ldsB0 = (char*)Bs + w * 1024;
  char* ldsB1 = ldsB0 + 4096;

  for (int k0 = 0; k0 < K; k0 += 32) {
    load_lds16(Ag + k0, ldsA0);
    load_lds16(Ag + (long)64 * K + k0, ldsA1);
    load_lds16(Bg + k0, ldsB0);
    load_lds16(Bg + (long)64 * K + k0, ldsB1);
    __syncthreads();
    bf16x8 af[4], bfv[4];
#pragma unroll
    for (int i = 0; i < 4; i++)
      af[i] = *(const bf16x8*)&As[(wr * 64 + i * 16 + ln) * 32 + quad * 8];
#pragma unroll
    for (int j = 0; j < 4; j++)
      bfv[j] = *(const bf16x8*)&Bs[(wc * 64 + j * 16 + ln) * 32 + quad * 8];
#pragma unroll
    for (int i = 0; i < 4; i++)
#pragma unroll
      for (int j = 0; j < 4; j++)
        acc[i][j] = __builtin_amdgcn_mfma_f32_16x16x32_bf16(af[i], bfv[j], acc[i][j], 0, 0, 0);
    __syncthreads();
  }

  int nb = n0 + wc * 64;                        // 64-aligned column block
  int type = nb >> 10, h = (nb >> 6) & 15;
  int b = (m0 >> 11);                           // 128-tiles never straddle batch
  int sl0 = (m0 & 2047) + wr * 64;              // within-batch s base for this wave
  long bhbase = (long)((b * 16 + h)) * 131072;  // bh * 2048 * 64

  if (type == 0) {
#pragma unroll
    for (int i = 0; i < 4; i++)
#pragma unroll
      for (int j = 0; j < 4; j++) {
        int d = j * 16 + ln;
#pragma unroll
        for (int rr = 0; rr < 4; rr++) {
          int s = sl0 + i * 16 + quad * 4 + rr;
          qh[bhbase + (long)s * 64 + d] = __float2bfloat16(acc[i][j][rr]);
        }
      }
  } else if (type == 1) {
#pragma unroll
    for (int i = 0; i < 4; i++)
#pragma unroll
      for (int j = 0; j < 4; j++) {
        int d = j * 16 + ln;
        int dpart = (d >> 5) * 512 + ((d >> 3) & 3) * 128 + (d & 7);
        int kb = (sl0 + i * 16) * 64;           // (k&~15)*64
#pragma unroll
        for (int rr = 0; rr < 4; rr++)
          kf[bhbase + kb + dpart + (quad * 4 + rr) * 8] = __float2bfloat16(acc[i][j][rr]);
      }
  } else {
#pragma unroll
    for (int i = 0; i < 4; i++)
#pragma unroll
      for (int j = 0; j < 4; j++) {
        // vf: rr runs contiguously -> one 8B packed store
        int off = (sl0 + (i >> 1) * 32) * 64 + j * 512 +
                  ((quad >> 1) + ((i & 1) << 1)) * 128 + ln * 8 + (quad & 1) * 4;
        bf16x4 pk = {(__bf16)acc[i][j][0], (__bf16)acc[i][j][1],
                     (__bf16)acc[i][j][2], (__bf16)acc[i][j][3]};
        *(bf16x4*)(vf + bhbase + off) = pk;
      }
  }
}

// ---------------------------------------------------------------------------
// Flash attention: LDS double-buffered K+V staging (round-6 structure, low
// VGPR) at 4 blocks/CU. Grid (32 bh, 32 qblk) = 1024 blocks; 4 waves x 16 q.
// LDS = 8KB P + 2x16KB KV = 40KB -> 4 blocks/CU; VGPR ~80 (no reg prefetch).
// ---------------------------------------------------------------------------
__global__ __launch_bounds__(256, 2) void attn_kernel(const bf16* __restrict__ qh,
                                                      const bf16* __restrict__ kf,
                                                      const bf16* __restrict__ vf,
                                                      const float* __restrict__ btab,
                                                      bf16* __restrict__ ctx) {
  __shared__ char PsRaw[4 * 2048];             // per-wave 2KB P buffer
  __shared__ char KV[2][16384];                // [buf][K 8KB | V 8KB]
  int t = threadIdx.x, w = t >> 6, lane = t & 63, ln = lane & 15, quad = lane >> 4;
  int bh = blockIdx.x, b = bh >> 4, h = bh & 15;
  int qw = blockIdx.y * 64 + w * 16;           // this wave's first q row

  const bf16* qbase = qh + (long)bh * S_ * 64;
  const bf16* kfb = kf + (long)bh * S_ * 64;
  const bf16* vfb = vf + (long)bh * S_ * 64;
  const float* bt = btab + h * 4096;
  char* myPs = PsRaw + w * 2048;
  int lbo = quad * 256 + ln * 16;              // lane byte offset inside 1KB frag

  // Q as B-operand: lane holds q = qw+ln, d = f*32+quad*8+j
  bf16x8 Qf0, Qf1;
  {
    const bf16* qr = qbase + (long)(qw + ln) * 64;
    Qf0 = *(const bf16x8*)(qr + quad * 8);
    Qf1 = *(const bf16x8*)(qr + 32 + quad * 8);
  }

  float cneg = bt[0], cpos = bt[4095];
  float l_acc = 0.f;
  floatx4 o[4];
  floatx4 zero = {0.f, 0.f, 0.f, 0.f};
#pragma unroll
  for (int dt = 0; dt < 4; dt++) o[dt] = zero;

  // stage tile 0 into buf 0: thread t moves bytes [t*16, t*16+16) of each 8KB
  {
    const bf16* kg = kfb + t * 8;
    const bf16* vg = vfb + t * 8;
    load_lds16(kg,        KV[0] + w * 1024);
    load_lds16(kg + 2048, KV[0] + 4096 + w * 1024);
    load_lds16(vg,        KV[0] + 8192 + w * 1024);
    load_lds16(vg + 2048, KV[0] + 12288 + w * 1024);
  }

  int pb = 0;
  for (int k0 = 0; k0 < S_; k0 += 64) {
    __syncthreads();                           // buf pb DMA done; prev reads done
    int kn = k0 + 64;
    if (kn < S_) {                             // issue next tile's DMA now
      const bf16* kg = kfb + (long)kn * 64 + t * 8;
      const bf16* vg = vfb + (long)kn * 64 + t * 8;
      char* nb_ = KV[pb ^ 1];
      load_lds16(kg,        nb_ + w * 1024);
      load_lds16(kg + 2048, nb_ + 4096 + w * 1024);
      load_lds16(vg,        nb_ + 8192 + w * 1024);
      load_lds16(vg + 2048, nb_ + 12288 + w * 1024);
    }

    const char* bK = KV[pb];
    const char* bV = KV[pb] + 8192;
    bf16x8 Kr[4][2], Vr[4][2];
#pragma unroll
    for (int tile = 0; tile < 4; tile++) {
      Kr[tile][0] = *(const bf16x8*)(bK + tile * 2048 + lbo);
      Kr[tile][1] = *(const bf16x8*)(bK + tile * 2048 + 1024 + lbo);
    }
#pragma unroll
    for (int f = 0; f < 2; f++)
#pragma unroll
      for (int dt = 0; dt < 4; dt++)
        Vr[dt][f] = *(const bf16x8*)(bV + f * 4096 + dt * 1024 + lbo);

    // S^T tiles: A = K, B = Q -> col = q = ln, row = k = quad*4+rr
    floatx4 st[4];
#pragma unroll
    for (int tile = 0; tile < 4; tile++) {
      st[tile] = __builtin_amdgcn_mfma_f32_16x16x32_bf16(Kr[tile][0], Qf0, zero, 0, 0, 0);
      st[tile] = __builtin_amdgcn_mfma_f32_16x16x32_bf16(Kr[tile][1], Qf1, st[tile], 0, 0, 0);
    }

    bool near = (k0 > qw - 192) && (k0 < qw + 144);
    if (near) {
#pragma unroll
      for (int tile = 0; tile < 4; tile++) {
        int bidx = k0 + tile * 16 + quad * 4 - (qw + ln) + 2048;
        float p0 = __builtin_amdgcn_exp2f(fmaf(st[tile][0], LOG2E, bt[bidx + 0]));
        float p1 = __builtin_amdgcn_exp2f(fmaf(st[tile][1], LOG2E, bt[bidx + 1]));
        float p2 = __builtin_amdgcn_exp2f(fmaf(st[tile][2], LOG2E, bt[bidx + 2]));
        float p3 = __builtin_amdgcn_exp2f(fmaf(st[tile][3], LOG2E, bt[bidx + 3]));
        l_acc += (p0 + p1) + (p2 + p3);
        bf16x4 pk = {(__bf16)p0, (__bf16)p1, (__bf16)p2, (__bf16)p3};
        int chunk = tile * 2 + (quad >> 1);
        *(bf16x4*)(myPs + (ln * 8 + (chunk ^ (ln & 7))) * 16 + (quad & 1) * 8) = pk;
      }
    } else {
      float cb = (k0 > qw) ? cpos : cneg;
#pragma unroll
      for (int tile = 0; tile < 4; tile++) {
        float p0 = __builtin_amdgcn_exp2f(fmaf(st[tile][0], LOG2E, cb));
        float p1 = __builtin_amdgcn_exp2f(fmaf(st[tile][1], LOG2E, cb));
        float p2 = __builtin_amdgcn_exp2f(fmaf(st[tile][2], LOG2E, cb));
        float p3 = __builtin_amdgcn_exp2f(fmaf(st[tile][3], LOG2E, cb));
        l_acc += (p0 + p1) + (p2 + p3);
        bf16x4 pk = {(__bf16)p0, (__bf16)p1, (__bf16)p2, (__bf16)p3};
        int chunk = tile * 2 + (quad >> 1);
        *(bf16x4*)(myPs + (ln * 8 + (chunk ^ (ln & 7))) * 16 + (quad & 1) * 8) = pk;
      }
    }

    // PV: A = P from per-wave LDS, B = V from staged LDS
    bf16x8 Pf0 = *(const bf16x8*)(myPs + (ln * 8 + (quad ^ (ln & 7))) * 16);
    bf16x8 Pf1 = *(const bf16x8*)(myPs + (ln * 8 + ((4 + quad) ^ (ln & 7))) * 16);
#pragma unroll
    for (int dt = 0; dt < 4; dt++) {
      o[dt] = __builtin_amdgcn_mfma_f32_16x16x32_bf16(Pf0, Vr[dt][0], o[dt], 0, 0, 0);
      o[dt] = __builtin_amdgcn_mfma_f32_16x16x32_bf16(Pf1, Vr[dt][1], o[dt], 0, 0, 0);
    }

    pb ^= 1;
  }

  // final l reduction across quads, then scale+store
  l_acc += __shfl_xor(l_acc, 16);
  l_acc += __shfl_xor(l_acc, 32);
#pragma unroll
  for (int rr = 0; rr < 4; rr++) {
    float linv = 1.0f / __shfl(l_acc, quad * 4 + rr);
    int q = qw + quad * 4 + rr;
#pragma unroll
    for (int dt = 0; dt < 4; dt++)
      ctx[(long)(b * S_ + q) * 1024 + h * 64 + dt * 16 + ln] =
          __float2bfloat16(o[dt][rr] * linv);
  }
}

// ---------------------------------------------------------------------------
// Out-proj GEMM: C[M][N] = A[M][K] * Bt[N][K]^T (fp32 out), m97-style staging.
// ---------------------------------------------------------------------------
__global__ __launch_bounds__(256) void gemm_bt_kernel(const bf16* __restrict__ A,
                                                      const bf16* __restrict__ Bt,
                                                      float* __restrict__ C,
                                                      int M, int N, int K) {
  __shared__ bf16 As[128 * 32];
  __shared__ bf16 Bs[128 * 32];
  int t = threadIdx.x;
  int m0 = blockIdx.y * 128, n0 = blockIdx.x * 128;
  int w = t >> 6, lane = t & 63, ln = lane & 15, quad = lane >> 4;
  int wr = w >> 1, wc = w & 1;
  floatx4 acc[4][4];
  floatx4 zero = {0.f, 0.f, 0.f, 0.f};
#pragma unroll
  for (int i = 0; i < 4; i++)
#pragma unroll
    for (int j = 0; j < 4; j++) acc[i][j] = zero;

  int r = t >> 2, c = (t & 3) * 8;
  const bf16* Ag = A + (long)(m0 + r) * K + c;
  const bf16* Bg = Bt + (long)(n0 + r) * K + c;
  char* ldsA0 = (char*)As + w * 1024;
  char* ldsA1 = ldsA0 + 4096;
  char* ldsB0 = (char*)Bs + w * 1024;
  char* ldsB1 = ldsB0 + 4096;

  for (int k0 = 0; k0 < K; k0 += 32) {
    load_lds16(Ag + k0, ldsA0);
    load_lds16(Ag + (long)64 * K + k0, ldsA1);
    load_lds16(Bg + k0, ldsB0);
    load_lds16(Bg + (long)64 * K + k0, ldsB1);
    __syncthreads();
    bf16x8 af[4], bfv[4];
#pragma unroll
    for (int i = 0; i < 4; i++)
      af[i] = *(const bf16x8*)&As[(wr * 64 + i * 16 + ln) * 32 + quad * 8];
#pragma unroll
    for (int j = 0; j < 4; j++)
      bfv[j] = *(const bf16x8*)&Bs[(wc * 64 + j * 16 + ln) * 32 + quad * 8];
#pragma unroll
    for (int i = 0; i < 4; i++)
#pragma unroll
      for (int j = 0; j < 4; j++)
        acc[i][j] = __builtin_amdgcn_mfma_f32_16x16x32_bf16(af[i], bfv[j], acc[i][j], 0, 0, 0);
    __syncthreads();
  }

#pragma unroll
  for (int i = 0; i < 4; i++)
#pragma unroll
    for (int j = 0; j < 4; j++)
#pragma unroll
      for (int rr = 0; rr < 4; rr++)
        C[(long)(m0 + wr * 64 + i * 16 + quad * 4 + rr) * N + n0 + wc * 64 + j * 16 + ln] =
            acc[i][j][rr];
}

// ---------------------------------------------------------------------------
extern "C" void kernel_launch(void* const* d_in, const int* in_sizes, int n_in,
                              void* d_out, int out_size, void* d_ws, size_t ws_size,
                              hipStream_t stream) {
  (void)in_sizes; (void)n_in; (void)out_size; (void)ws_size;
  const float* hidden   = (const float*)d_in[0];
  const float* Wq       = (const float*)d_in[1];
  const float* Wk       = (const float*)d_in[2];
  const float* Wv       = (const float*)d_in[3];
  const float* Wo       = (const float*)d_in[4];
  const float* rel_bias = (const float*)d_in[5];

  char* ws = (char*)d_ws;
  bf16*  hbf    = (bf16*)(ws + 0);                 //  8 MB [4096][1024]
  bf16*  wt_qkv = (bf16*)(ws + 8388608);           //  6 MB
  bf16*  wt_o   = (bf16*)(ws + 14680064);          //  2 MB
  float* btab   = (float*)(ws + 16777216);         // 256 KB
  bf16*  qh     = (bf16*)(ws + 17039360);          //  8 MB head-major Q
  bf16*  kf     = (bf16*)(ws + 25427968);          //  8 MB frag-major K
  bf16*  vf     = (bf16*)(ws + 33816576);          //  8 MB frag-major V
  bf16*  ctx    = (bf16*)(ws + 42205184);          //  8 MB

  cast_f32_bf16_kernel<<<dim3(4096), dim3(256), 0, stream>>>(hidden, hbf);
  transpose_w_kernel<<<dim3(32, 32, 4), dim3(32, 8), 0, stream>>>(Wq, Wk, Wv, Wo, wt_qkv, wt_o);
  bias_table_kernel<<<dim3(256), dim3(256), 0, stream>>>(rel_bias, btab);
  gemm_qkv_kernel<<<dim3(24, 32), dim3(256), 0, stream>>>(hbf, wt_qkv, qh, kf, vf);
  attn_kernel<<<dim3(32, 32), dim3(256), 0, stream>>>(qh, kf, vf, btab, ctx);
  gemm_bt_kernel<<<dim3(8, 32), dim3(256), 0, stream>>>(ctx, wt_o, (float*)d_out, 4096, 1024, 1024);
}